// Round 10
// baseline (572.537 us; speedup 1.0000x reference)
//
#include <hip/hip_runtime.h>
#include <math.h>

constexpr float CC   = 1.2f;
constexpr float SQC  = 1.09544511501033215f;      // sqrt(1.2)
constexpr float MAXN = (1.0f - 4e-3f) / SQC;      // geoopt projx maxnorm
constexpr float MINN = 1e-15f;

// ---------------- ws float offsets (transposed padded weights + constants) ----
constexpr int WTH1 = 0;        // [32][128]
constexpr int WTH2 = 4096;     // [80][128]
constexpr int WTH3 = 14336;    // [104][128]
constexpr int WTAH = 27648;    // [128][128]
constexpr int WTE1 = 44032;    // [32][128]
constexpr int WTE2 = 48128;    // [80][128]
constexpr int WTE3 = 58368;    // [104][128]
constexpr int EB1  = 71680;    // expmap0(bh1) padded 128
constexpr int EB2  = 71808;
constexpr int EB3  = 71936;
constexpr int EBA  = 72064;
constexpr int BE1  = 72192;    // be1 padded 128
constexpr int BE2  = 72320;
constexpr int BE3  = 72448;
constexpr int U1o  = 72576;    // Wae^T wte
constexpr int U2o  = 72704;    // Wae^T wth
constexpr int SCo  = 72832;    // c1,c2,y2h1,y2h2,y2h3,y2ah,EBW1,EBW2
constexpr int PART = 72864;    // 8192 wave-groups x 10 classifier partials

constexpr int ASTR = 17;       // ACT row stride (16 tokens + 1 pad)
constexpr int AWV  = 128*ASTR; // per-wave ACT region (floats)

// ---------------- scalar math ----------------
__device__ __forceinline__ float art_(float x){
  x = fminf(fmaxf(x, -0.9999999f), 0.9999999f);
  return 0.5f * __logf((1.0f + x) / (1.0f - x));
}
__device__ __forceinline__ float tanh_(float x){
  x = fminf(fmaxf(x, -15.0f), 15.0f);
  float e = __expf(2.0f * x);
  return (e - 1.0f) / (e + 1.0f);
}
__device__ __forceinline__ float wsum(float v){
#pragma unroll
  for(int i=32;i>0;i>>=1) v += __shfl_xor(v, i, 64);
  return v;
}
// butterfly over the 16 fj lanes -> ALL lanes end with the full per-token sum
__device__ __forceinline__ float rtj(float v){
  v += __shfl_xor(v, 1, 64); v += __shfl_xor(v, 2, 64);
  v += __shfl_xor(v, 4, 64); v += __shfl_xor(v, 8, 64);
  return v;
}
// select a[i] with runtime i in 0..3 (pure cndmask, no scratch)
__device__ __forceinline__ float sel4(const float (&a)[4], int i){
  float lo = (i & 1) ? a[1] : a[0];
  float hi = (i & 1) ? a[3] : a[2];
  return (i & 2) ? hi : lo;
}
// broadcast from the lane (same tt-group) that owns token i: lane = (ln&~3)|i
__device__ __forceinline__ float bcx(float v, int ln, int i){
  return __shfl(v, (ln & 60) | i, 64);
}
__device__ __forceinline__ float lamv(float nv){
  float n = fmaxf(nv, MINN);
  return art_(SQC*n)/(SQC*n);
}
struct HS { float ca, cb, nv; };
__device__ __forceinline__ HS hyper_chain(float m2, float meb, float xn_in, float y2){
  float xn  = fmaxf(xn_in, MINN);
  float mxn = fmaxf(sqrtf(m2), MINN);
  float r   = art_(SQC*xn);
  float s   = tanh_(mxn/xn*r)/(mxn*SQC);
  float nr  = s*mxn;
  if(nr > MAXN){ s *= MAXN/nr; nr = MAXN; }
  float xy = s*meb, x2 = nr*nr;
  float den = fmaxf(1.f + 2.f*CC*xy + CC*CC*x2*y2, MINN);
  float A   = (1.f + 2.f*CC*xy + CC*y2)/den;
  float Bc  = (1.f - CC*x2)/den;
  float n3  = sqrtf(fmaxf(A*A*x2 + 2.f*A*Bc*xy + Bc*Bc*y2, 0.f));
  float rho = (n3 > MAXN) ? MAXN/n3 : 1.f;
  HS h; h.nv = fminf(n3, MAXN); h.ca = rho*A*s; h.cb = rho*Bc;
  return h;
}
struct TT { float tau, nf; };
__device__ __forceinline__ TT tail_relu(float rn2){
  float rn = fmaxf(sqrtf(rn2), MINN);
  float th = tanh_(SQC*rn);
  TT r; r.tau = th/(SQC*rn); r.nf = th/SQC;
  if(r.nf > MAXN){ r.tau *= MAXN/r.nf; r.nf = MAXN; }
  return r;
}
struct EX { float nh, scl; };
__device__ __forceinline__ EX exp0(float n2){
  float n0 = fmaxf(sqrtf(n2), MINN);
  float th = tanh_(SQC*n0);
  EX e; e.nh = th/SQC; e.scl = th/(SQC*n0);
  if(e.nh > MAXN){ e.scl *= MAXN/e.nh; e.nh = MAXN; }
  return e;
}
struct THW { float te, th2; };
__device__ __forceinline__ THW ahchain(float m2a, float mw1, float mw2, float meba,
                                       float xnh, float rr, float y2,
                                       float ebw1, float ebw2){
  float mxn = fmaxf(sqrtf(m2a), MINN);
  float s = tanh_(mxn/xnh*rr)/(mxn*SQC);
  float nr = s*mxn;
  if(nr > MAXN){ s *= MAXN/nr; nr = MAXN; }
  float xy = s*meba, x2 = nr*nr;
  float den = fmaxf(1.f + 2.f*CC*xy + CC*CC*x2*y2, MINN);
  float A = (1.f + 2.f*CC*xy + CC*y2)/den;
  float Bc = (1.f - CC*x2)/den;
  float n3 = sqrtf(fmaxf(A*A*x2 + 2.f*A*Bc*xy + Bc*Bc*y2, 0.f));
  float rho = (n3 > MAXN) ? MAXN/n3 : 1.f;
  float nv = fminf(n3, MAXN);
  float lr = lamv(nv)*rho;
  THW r; r.te = lr*(A*s*mw1 + Bc*ebw1); r.th2 = lr*(A*s*mw2 + Bc*ebw2);
  return r;
}
struct AG { float wge, g2; };
__device__ __forceinline__ AG attn(float d1, float d2, float thte, float thth,
                                   float rr, float xnh, float b_e, float b_h){
  float a_e = 0.5f*(d1 - thte) + b_e;
  float a_h = 0.5f*(thth - d2) + b_h;
  float mx = fmaxf(a_e, a_h);
  float ee = __expf(a_e - mx), eh = __expf(a_h - mx);
  float inv = 1.f/(ee + eh);
  AG r; r.wge = ee*inv;
  float wgh = eh*inv;
  float inner = wgh*rr;
  float scl2 = tanh_(inner)/(xnh*SQC);
  float nn = scl2*xnh;
  if(nn > MAXN){ scl2 *= MAXN/nn; nn = MAXN; }
  r.g2 = lamv(nn)*scl2;
  return r;
}

// ---------------- fused setup: transpose-pad weights + folded constants ------
// grid 281 x 256: blocks 0..279 transpose 2 rows each; block 280 = constants.
__global__ void k_setup(const float* __restrict__ Wh1, const float* __restrict__ Wh2,
                        const float* __restrict__ Wh3, const float* __restrict__ Wah,
                        const float* __restrict__ We1, const float* __restrict__ We2,
                        const float* __restrict__ We3,
                        const float* __restrict__ Wae, const float* __restrict__ bae,
                        const float* __restrict__ bh1, const float* __restrict__ bh2,
                        const float* __restrict__ bh3, const float* __restrict__ bah,
                        const float* __restrict__ Wte, const float* __restrict__ Wth,
                        const float* __restrict__ be1, const float* __restrict__ be2,
                        const float* __restrict__ be3, float* __restrict__ ws){
  const int blk = blockIdx.x, tid = threadIdx.x;
  if(blk < 280){
    const int row = blk*2 + (tid >> 7);   // 0..559
    const int j   = tid & 127;
    const float* W; int OUT, K, kk, dst;
    if(row < 32)       { W=Wh1; OUT=80;  K=32;  kk=row;      dst=WTH1; }
    else if(row < 112) { W=Wh2; OUT=104; K=80;  kk=row-32;   dst=WTH2; }
    else if(row < 216) { W=Wh3; OUT=128; K=104; kk=row-112;  dst=WTH3; }
    else if(row < 344) { W=Wah; OUT=128; K=128; kk=row-216;  dst=WTAH; }
    else if(row < 376) { W=We1; OUT=80;  K=32;  kk=row-344;  dst=WTE1; }
    else if(row < 456) { W=We2; OUT=104; K=80;  kk=row-376;  dst=WTE2; }
    else               { W=We3; OUT=128; K=104; kk=row-456;  dst=WTE3; }
    ws[dst + kk*128 + j] = (j < OUT) ? W[j*K + kk] : 0.f;
    return;
  }
  // -------- constants block --------
  {
    const int which = tid >> 7, k = tid & 127;
    const float* wv = which ? Wth : Wte;
    float s = 0.f;
#pragma unroll 4
    for(int j=0;j<128;++j) s += Wae[j*128+k] * wv[j];
    ws[(which ? U2o : U1o) + k] = s;
  }
  if(tid < 128){
    ws[BE1+tid] = (tid < 80)  ? be1[tid] : 0.f;
    ws[BE2+tid] = (tid < 104) ? be2[tid] : 0.f;
    ws[BE3+tid] = be3[tid];
  }
  if(tid < 64){
    const int l = tid;
    float p1=0.f, p2=0.f;
    for(int j=l;j<128;j+=64){ p1 += bae[j]*Wte[j]; p2 += bae[j]*Wth[j]; }
    p1 = wsum(p1); p2 = wsum(p2);
    if(l==0){ ws[SCo+0]=p1; ws[SCo+1]=p2; }
    const float* bs[4] = {bh1,bh2,bh3,bah};
    const int dims[4]  = {80,104,128,128};
    const int offs[4]  = {EB1,EB2,EB3,EBA};
    for(int v=0;v<4;++v){
      const float* bp = bs[v]; const int D = dims[v];
      float q = 0.f;
      for(int j=l;j<D;j+=64) q += bp[j]*bp[j];
      q = wsum(q);
      float nb = fmaxf(sqrtf(q), MINN);
      float th = tanhf(fminf(fmaxf(SQC*nb,-15.f),15.f));
      float coef = th/(SQC*nb);
      float ne = th/SQC;
      if(ne > MAXN){ coef *= MAXN/ne; ne = MAXN; }
      for(int j=l;j<D;j+=64) ws[offs[v]+j] = coef*bp[j];
      for(int j=D+l;j<128;j+=64) ws[offs[v]+j] = 0.f;   // pad
      if(l==0) ws[SCo+2+v] = ne*ne;
      if(v==3){
        float e1=0.f, e2=0.f;
        for(int j=l;j<D;j+=64){ e1 += bp[j]*Wte[j]; e2 += bp[j]*Wth[j]; }
        e1 = wsum(e1)*coef; e2 = wsum(e2)*coef;
        if(l==0){ ws[SCo+6]=e1; ws[SCo+7]=e2; }
      }
    }
  }
}

// ---------------- finishing kernel: combine 8 sixteenths + classifier --------
__global__ void k_fin(const float* __restrict__ ws, const float* __restrict__ bf1,
                      const float* __restrict__ Wf2, const float* __restrict__ bf2,
                      float* __restrict__ out){
  const int r = blockIdx.x*64 + threadIdx.x;   // grid 16 x 64 = 1024 rows
  const float* p = ws + PART + (size_t)r*80;   // 8 wave-groups x 10
  float f1[10];
#pragma unroll
  for(int i=0;i<10;++i){
    float s = 0.f;
#pragma unroll
    for(int g=0;g<8;++g) s += p[g*10+i];
    // each token was counted 4x by the owner-lane redundancy -> /(128*4)
    f1[i] = fmaxf(s*(1.f/512.f) + bf1[i], 0.f);
  }
#pragma unroll
  for(int o=0;o<10;++o){
    float a = bf2[o];
#pragma unroll
    for(int k=0;k<10;++k) a = fmaf(Wf2[o*10+k], f1[k], a);
    out[r*10 + o] = a;
  }
}

// ---------------- GEMM inner: 8 feat x 4 tok register tile per lane ----------
__device__ __forceinline__ void ld8(const float* __restrict__ p, float (&v)[8]){
  float4 a = *(const float4*)p, b = *(const float4*)(p+4);
  v[0]=a.x; v[1]=a.y; v[2]=a.z; v[3]=a.w; v[4]=b.x; v[5]=b.y; v[6]=b.z; v[7]=b.w;
}

// unroll 4: with the 128-VGPR budget (2-wave workgroup) the scheduler can keep
// the next group's loads in flight across the FMA block (vmcnt(N) not 0).
template<int K, bool XG, bool XSQ>
__device__ __forceinline__ void gemmw(const float* __restrict__ wt,
                                      const float* __restrict__ xg,
                                      const float* __restrict__ ACT,
                                      int fj, int tt, float (&acc)[4][8], float (&xsq)[4]){
#pragma unroll
  for(int i=0;i<4;++i)
#pragma unroll
    for(int j=0;j<8;++j) acc[i][j] = 0.f;
  const int wo = fj*8, xo = tt*4;
#pragma unroll 4
  for(int k=0;k<K;++k){
    float4 w0 = *(const float4*)(wt + k*128 + wo);
    float4 w1 = *(const float4*)(wt + k*128 + wo + 4);
    float4 xa;
    if(XG) xa = *(const float4*)(xg + k*128 + xo);
    else   xa = *(const float4*)(ACT + k*ASTR + xo);
    float xv[4] = {xa.x,xa.y,xa.z,xa.w};
    float wv[8] = {w0.x,w0.y,w0.z,w0.w,w1.x,w1.y,w1.z,w1.w};
#pragma unroll
    for(int i=0;i<4;++i){
      if(XSQ) xsq[i] = fmaf(xv[i], xv[i], xsq[i]);
#pragma unroll
      for(int j=0;j<8;++j) acc[i][j] = fmaf(xv[i], wv[j], acc[i][j]);
    }
  }
}

__device__ __forceinline__ void wACT(float* __restrict__ ACT, const float (&acc)[4][8],
                                     int fj, int tt){
#pragma unroll
  for(int j=0;j<8;++j){
    float4 a = {acc[0][j],acc[1][j],acc[2][j],acc[3][j]};
    *(float4*)(ACT + (fj*8+j)*ASTR + tt*4) = a;
  }
}

// ---------------- main kernel: 128 thr = 2 INDEPENDENT WAVES, 16 tokens each -
// Packaging dodge for the allocator: 1-wave workgroups are pinned at 64 VGPR
// (R3-R9, immune to attributes); multi-wave workgroups follow cap=512/(2*min)
// with demand-sized allocation (R0/R1/R2). __launch_bounds__(128,2) -> 128 cap.
// Each wave owns a private ACT/ZH region -> still ZERO __syncthreads.
__global__ __launch_bounds__(128, 2) void k_main(
    const float* __restrict__ x,
    const float* __restrict__ Wf1, const float* __restrict__ Wte,
    const float* __restrict__ bte, const float* __restrict__ Wth,
    const float* __restrict__ bth, float* __restrict__ ws){
  __shared__ float ACTs[2*AWV];         // 2 x 8704 B
  __shared__ float ZHs[2*160];          // 2 x (10 classes x 16 tokens)
  const int tid = threadIdx.x, w = tid >> 6, ln = tid & 63;
  const int fj = ln & 15, tt = ln >> 4;
  const int b = blockIdx.x, row = b >> 2, q = b & 3;
  const int own = fj & 3;               // token (within my tt group) I own
  float* ACT = ACTs + w*AWV;
  float* ZH  = ZHs  + w*160;
  const int gw = b*2 + w;               // global wave index (0..8191)
  const float* xg = x + (size_t)row*4096 + q*32 + w*16;

  // wave-uniform constants (scalar loads)
  const float c1  = ws[SCo+0], c2  = ws[SCo+1];
  const float y21 = ws[SCo+2], y22 = ws[SCo+3], y23 = ws[SCo+4], y2a = ws[SCo+5];
  const float ew1 = ws[SCo+6], ew2 = ws[SCo+7];
  const float btev = bte[0], bthv = bth[0];

  float acc[4][8];
  float xsq[4];
#pragma unroll
  for(int i=0;i<4;++i) xsq[i] = 0.f;

  // owner-lane per-token state
  float nfO = 0.f, xnhO = 1.f, rrO = 0.f, tteO = 0.f, tthO = 0.f;

  // ================= H1: 32 -> 128(pad80), mob_relu =================
  {
    gemmw<32,true,true>(ws+WTH1, xg, ACT, fj, tt, acc, xsq);
    float ebv[8]; ld8(ws+EB1+fj*8, ebv);
    float sO = 0.f, eO = 0.f;
#pragma unroll
    for(int i=0;i<4;++i){
      float s=0.f, e=0.f;
#pragma unroll
      for(int j=0;j<8;++j){ s = fmaf(acc[i][j],acc[i][j],s); e = fmaf(acc[i][j],ebv[j],e); }
      s = rtj(s); e = rtj(e);                   // full sums in ALL lanes
      if(own==i){ sO = s; eO = e; }             // running owner-select
    }
    EX e0 = exp0(sel4(xsq, own));
    HS h  = hyper_chain(sO*e0.scl*e0.scl, eO*e0.scl, e0.nh, y21);
    float lam = lamv(h.nv);
    float Aw = lam*h.ca*e0.scl, Bw = lam*h.cb;
    float s2O = 0.f;
#pragma unroll
    for(int i=0;i<4;++i){
      float Ab = bcx(Aw,ln,i), Bb = bcx(Bw,ln,i);
      float s2 = 0.f;
#pragma unroll
      for(int j=0;j<8;++j){
        float v = fmaxf(fmaf(Ab, acc[i][j], Bb*ebv[j]), 0.f);
        acc[i][j] = v; s2 = fmaf(v,v,s2);
      }
      s2 = rtj(s2);
      if(own==i) s2O = s2;
    }
    TT tr = tail_relu(s2O);
    nfO = tr.nf;
#pragma unroll
    for(int i=0;i<4;++i){
      float tb = bcx(tr.tau,ln,i);
#pragma unroll
      for(int j=0;j<8;++j) acc[i][j] *= tb;
    }
    wACT(ACT, acc, fj, tt);
  }

  // ================= H2: 80 -> 128(pad104), mob_relu =================
  {
    gemmw<80,false,false>(ws+WTH2, nullptr, ACT, fj, tt, acc, xsq);
    float ebv[8]; ld8(ws+EB2+fj*8, ebv);
    float sO = 0.f, eO = 0.f;
#pragma unroll
    for(int i=0;i<4;++i){
      float s=0.f, e=0.f;
#pragma unroll
      for(int j=0;j<8;++j){ s = fmaf(acc[i][j],acc[i][j],s); e = fmaf(acc[i][j],ebv[j],e); }
      s = rtj(s); e = rtj(e);
      if(own==i){ sO = s; eO = e; }
    }
    HS h = hyper_chain(sO, eO, nfO, y22);
    float lam = lamv(h.nv);
    float Aw = lam*h.ca, Bw = lam*h.cb;
    float s2O = 0.f;
#pragma unroll
    for(int i=0;i<4;++i){
      float Ab = bcx(Aw,ln,i), Bb = bcx(Bw,ln,i);
      float s2 = 0.f;
#pragma unroll
      for(int j=0;j<8;++j){
        float v = fmaxf(fmaf(Ab, acc[i][j], Bb*ebv[j]), 0.f);
        acc[i][j] = v; s2 = fmaf(v,v,s2);
      }
      s2 = rtj(s2);
      if(own==i) s2O = s2;
    }
    TT tr = tail_relu(s2O);
    nfO = tr.nf;
#pragma unroll
    for(int i=0;i<4;++i){
      float tb = bcx(tr.tau,ln,i);
#pragma unroll
      for(int j=0;j<8;++j) acc[i][j] *= tb;
    }
    wACT(ACT, acc, fj, tt);
  }

  // ================= H3: 104 -> 128, p_linear only (out_h) =================
  {
    gemmw<104,false,false>(ws+WTH3, nullptr, ACT, fj, tt, acc, xsq);
    float ebv[8]; ld8(ws+EB3+fj*8, ebv);
    float sO = 0.f, eO = 0.f;
#pragma unroll
    for(int i=0;i<4;++i){
      float s=0.f, e=0.f;
#pragma unroll
      for(int j=0;j<8;++j){ s = fmaf(acc[i][j],acc[i][j],s); e = fmaf(acc[i][j],ebv[j],e); }
      s = rtj(s); e = rtj(e);
      if(own==i){ sO = s; eO = e; }
    }
    HS h = hyper_chain(sO, eO, nfO, y23);
    xnhO = fmaxf(h.nv, MINN);
    rrO  = art_(SQC*xnhO);
#pragma unroll
    for(int i=0;i<4;++i){
      float ca = bcx(h.ca,ln,i), cb = bcx(h.cb,ln,i);
#pragma unroll
      for(int j=0;j<8;++j) acc[i][j] = fmaf(ca, acc[i][j], cb*ebv[j]);
    }
    wACT(ACT, acc, fj, tt);
    // zh[ic][token] = Wf1[ic,128+.] . out_h  -> per-wave LDS
#pragma unroll
    for(int ic=0;ic<10;++ic){
      float wf[8]; ld8(Wf1 + ic*256 + 128 + fj*8, wf);
#pragma unroll
      for(int i=0;i<4;++i){
        float s=0.f;
#pragma unroll
        for(int j=0;j<8;++j) s = fmaf(acc[i][j], wf[j], s);
        s = rtj(s);
        if(fj==0) ZH[ic*16 + tt*4 + i] = s;
      }
    }
  }

  // ================= Wah pass: 4 reductions of mx = Wah . out_h =============
  {
    gemmw<128,false,false>(ws+WTAH, nullptr, ACT, fj, tt, acc, xsq);
    float w1v[8], w2v[8], eav[8];
    ld8(Wte + fj*8, w1v); ld8(Wth + fj*8, w2v); ld8(ws+EBA+fj*8, eav);
    float aO=0.f, bO=0.f, cO=0.f, dO=0.f;
#pragma unroll
    for(int i=0;i<4;++i){
      float s0=0.f,s1=0.f,s2=0.f,s3=0.f;
#pragma unroll
      for(int j=0;j<8;++j){
        float m = acc[i][j];
        s0 = fmaf(m,m,s0); s1 = fmaf(m,w1v[j],s1);
        s2 = fmaf(m,w2v[j],s2); s3 = fmaf(m,eav[j],s3);
      }
      s0=rtj(s0); s1=rtj(s1); s2=rtj(s2); s3=rtj(s3);
      if(own==i){ aO=s0; bO=s1; cO=s2; dO=s3; }
    }
    THW a = ahchain(aO, bO, cO, dO, xnhO, rrO, y2a, ew1, ew2);
    tteO = a.te; tthO = a.th2;
  }

  // ================= E1: relu(We1 x + be1) =================
  {
    gemmw<32,true,false>(ws+WTE1, xg, ACT, fj, tt, acc, xsq);
    float bev[8]; ld8(ws+BE1+fj*8, bev);
#pragma unroll
    for(int i=0;i<4;++i)
#pragma unroll
      for(int j=0;j<8;++j) acc[i][j] = fmaxf(acc[i][j]+bev[j], 0.f);
    wACT(ACT, acc, fj, tt);
  }
  // ================= E2 =================
  {
    gemmw<80,false,false>(ws+WTE2, nullptr, ACT, fj, tt, acc, xsq);
    float bev[8]; ld8(ws+BE2+fj*8, bev);
#pragma unroll
    for(int i=0;i<4;++i)
#pragma unroll
      for(int j=0;j<8;++j) acc[i][j] = fmaxf(acc[i][j]+bev[j], 0.f);
    wACT(ACT, acc, fj, tt);
  }
  // ======== E3: out_e (in regs) -> d1,d2, ze; attention; partials ========
  {
    gemmw<104,false,false>(ws+WTE3, nullptr, ACT, fj, tt, acc, xsq);
    float bev[8], u1v[8], u2v[8];
    ld8(ws+BE3+fj*8, bev); ld8(ws+U1o+fj*8, u1v); ld8(ws+U2o+fj*8, u2v);
    float s1O = 0.f, s2O = 0.f;
#pragma unroll
    for(int i=0;i<4;++i){
      float s1=0.f, s2=0.f;
#pragma unroll
      for(int j=0;j<8;++j){
        float v = fmaxf(acc[i][j]+bev[j], 0.f);
        acc[i][j] = v;
        s1 = fmaf(v,u1v[j],s1); s2 = fmaf(v,u2v[j],s2);
      }
      s1 = rtj(s1); s2 = rtj(s2);
      if(own==i){ s1O = s1; s2O = s2; }
    }
    AG g = attn(s1O + c1, s2O + c2, tteO, tthO, rrO, xnhO, btev, bthv);
    // classifier partials (each token counted 4x by owner redundancy; k_fin /512)
#pragma unroll
    for(int ic=0;ic<10;++ic){
      float wf[8]; ld8(Wf1 + ic*256 + fj*8, wf);
      float zO = 0.f;
#pragma unroll
      for(int i=0;i<4;++i){
        float s=0.f;
#pragma unroll
        for(int j=0;j<8;++j) s = fmaf(acc[i][j], wf[j], s);
        s = rtj(s);
        if(own==i) zO = s;
      }
      float p = g.wge*zO + g.g2*ZH[ic*16 + tt*4 + own];
      p = wsum(p);
      if(ln == 0) ws[PART + (size_t)gw*10 + ic] = p;
    }
  }
}

extern "C" void kernel_launch(void* const* d_in, const int* in_sizes, int n_in,
                              void* d_out, int out_size, void* d_ws, size_t ws_size,
                              hipStream_t stream){
  (void)in_sizes; (void)n_in; (void)out_size; (void)ws_size;
  const float* x   = (const float*)d_in[0];
  const float* We1 = (const float*)d_in[1];
  const float* be1 = (const float*)d_in[2];
  const float* We2 = (const float*)d_in[3];
  const float* be2 = (const float*)d_in[4];
  const float* We3 = (const float*)d_in[5];
  const float* be3 = (const float*)d_in[6];
  const float* Wh1 = (const float*)d_in[7];
  const float* bh1 = (const float*)d_in[8];
  const float* Wh2 = (const float*)d_in[9];
  const float* bh2 = (const float*)d_in[10];
  const float* Wh3 = (const float*)d_in[11];
  const float* bh3 = (const float*)d_in[12];
  const float* Wae = (const float*)d_in[13];
  const float* bae = (const float*)d_in[14];
  const float* Wah = (const float*)d_in[15];
  const float* bah = (const float*)d_in[16];
  const float* Wte = (const float*)d_in[17];
  const float* bte = (const float*)d_in[18];
  const float* Wth = (const float*)d_in[19];
  const float* bth = (const float*)d_in[20];
  const float* Wf1 = (const float*)d_in[21];
  const float* bf1 = (const float*)d_in[22];
  const float* Wf2 = (const float*)d_in[23];
  const float* bf2 = (const float*)d_in[24];
  float* ws  = (float*)d_ws;
  float* out = (float*)d_out;

  hipLaunchKernelGGL(k_setup, dim3(281), dim3(256), 0, stream,
                     Wh1, Wh2, Wh3, Wah, We1, We2, We3,
                     Wae, bae, bh1, bh2, bh3, bah, Wte, Wth, be1, be2, be3, ws);

  hipLaunchKernelGGL(k_main, dim3(4096), dim3(128), 0, stream,
                     x, Wf1, Wte, bte, Wth, bth, ws);

  hipLaunchKernelGGL(k_fin, dim3(16), dim3(64), 0, stream,
                     ws, bf1, Wf2, bf2, out);
}

// Round 11
// 516.422 us; speedup vs baseline: 1.1087x; 1.1087x over previous
//
#include <hip/hip_runtime.h>
#include <math.h>

constexpr float CC   = 1.2f;
constexpr float SQC  = 1.09544511501033215f;      // sqrt(1.2)
constexpr float MAXN = (1.0f - 4e-3f) / SQC;      // geoopt projx maxnorm
constexpr float MINN = 1e-15f;

// ---------------- ws float offsets (transposed padded weights + constants) ----
constexpr int WTH1 = 0;        // [32][128]
constexpr int WTH2 = 4096;     // [80][128]
constexpr int WTH3 = 14336;    // [104][128]
constexpr int WTAH = 27648;    // [128][128]
constexpr int WTE1 = 44032;    // [32][128]
constexpr int WTE2 = 48128;    // [80][128]
constexpr int WTE3 = 58368;    // [104][128]
constexpr int EB1  = 71680;    // expmap0(bh1) padded 128
constexpr int EB2  = 71808;
constexpr int EB3  = 71936;
constexpr int EBA  = 72064;
constexpr int BE1  = 72192;    // be1 padded 128
constexpr int BE2  = 72320;
constexpr int BE3  = 72448;
constexpr int U1o  = 72576;    // Wae^T wte
constexpr int U2o  = 72704;    // Wae^T wth
constexpr int SCo  = 72832;    // c1,c2,y2h1,y2h2,y2h3,y2ah,EBW1,EBW2
constexpr int PART = 72864;    // 8192 blocks x 10 classifier partials

constexpr int ASTR = 17;       // ACT row stride (16 tokens + 1 pad)

// ---------------- DPP cross-lane (VALU pipe, not DS) ----------------
// rtj reduces over the 16 contiguous fj lanes (ln&15) = one DPP row.
template<int CTRL>
__device__ __forceinline__ float dppa(float v){
  int x = __builtin_amdgcn_update_dpp(0, __float_as_int(v), CTRL, 0xf, 0xf, true);
  return v + __int_as_float(x);
}
// quad_perm xor1 = (1,0,3,2) -> 0xB1 ; xor2 = (2,3,0,1) -> 0x4E
// row_ror:4 = 0x124 ; row_ror:8 = 0x128
__device__ __forceinline__ float rtj(float v){
  v = dppa<0xB1>(v);
  v = dppa<0x4E>(v);
  v = dppa<0x124>(v);
  v = dppa<0x128>(v);
  return v;
}
// broadcast quad member I to all 4 lanes of each quad (1 VALU op)
template<int I>
__device__ __forceinline__ float qbc(float v){
  constexpr int c = I | (I<<2) | (I<<4) | (I<<6);
  return __int_as_float(__builtin_amdgcn_update_dpp(0, __float_as_int(v), c, 0xf, 0xf, true));
}
__device__ __forceinline__ float wsum(float v){
  v = rtj(v);                     // row16 totals via DPP
  v += __shfl_xor(v, 16, 64);
  v += __shfl_xor(v, 32, 64);
  return v;
}
// full-wave sum for setup kernel (keep simple shfl version)
__device__ __forceinline__ float wsum64(float v){
#pragma unroll
  for(int i=32;i>0;i>>=1) v += __shfl_xor(v, i, 64);
  return v;
}
// select a[i] with runtime i in 0..3 (pure cndmask, no scratch)
__device__ __forceinline__ float sel4(const float (&a)[4], int i){
  float lo = (i & 1) ? a[1] : a[0];
  float hi = (i & 1) ? a[3] : a[2];
  return (i & 2) ? hi : lo;
}

// ---------------- scalar math ----------------
__device__ __forceinline__ float art_(float x){
  x = fminf(fmaxf(x, -0.9999999f), 0.9999999f);
  return 0.5f * __logf((1.0f + x) / (1.0f - x));
}
__device__ __forceinline__ float tanh_(float x){
  x = fminf(fmaxf(x, -15.0f), 15.0f);
  float e = __expf(2.0f * x);
  return (e - 1.0f) / (e + 1.0f);
}
__device__ __forceinline__ float lamv(float nv){
  float n = fmaxf(nv, MINN);
  return art_(SQC*n)/(SQC*n);
}
struct HS { float ca, cb, nv; };
__device__ __forceinline__ HS hyper_chain(float m2, float meb, float xn_in, float y2){
  float xn  = fmaxf(xn_in, MINN);
  float mxn = fmaxf(sqrtf(m2), MINN);
  float r   = art_(SQC*xn);
  float s   = tanh_(mxn/xn*r)/(mxn*SQC);
  float nr  = s*mxn;
  if(nr > MAXN){ s *= MAXN/nr; nr = MAXN; }
  float xy = s*meb, x2 = nr*nr;
  float den = fmaxf(1.f + 2.f*CC*xy + CC*CC*x2*y2, MINN);
  float A   = (1.f + 2.f*CC*xy + CC*y2)/den;
  float Bc  = (1.f - CC*x2)/den;
  float n3  = sqrtf(fmaxf(A*A*x2 + 2.f*A*Bc*xy + Bc*Bc*y2, 0.f));
  float rho = (n3 > MAXN) ? MAXN/n3 : 1.f;
  HS h; h.nv = fminf(n3, MAXN); h.ca = rho*A*s; h.cb = rho*Bc;
  return h;
}
struct TT { float tau, nf; };
__device__ __forceinline__ TT tail_relu(float rn2){
  float rn = fmaxf(sqrtf(rn2), MINN);
  float th = tanh_(SQC*rn);
  TT r; r.tau = th/(SQC*rn); r.nf = th/SQC;
  if(r.nf > MAXN){ r.tau *= MAXN/r.nf; r.nf = MAXN; }
  return r;
}
struct EX { float nh, scl; };
__device__ __forceinline__ EX exp0(float n2){
  float n0 = fmaxf(sqrtf(n2), MINN);
  float th = tanh_(SQC*n0);
  EX e; e.nh = th/SQC; e.scl = th/(SQC*n0);
  if(e.nh > MAXN){ e.scl *= MAXN/e.nh; e.nh = MAXN; }
  return e;
}
struct THW { float te, th2; };
__device__ __forceinline__ THW ahchain(float m2a, float mw1, float mw2, float meba,
                                       float xnh, float rr, float y2,
                                       float ebw1, float ebw2){
  float mxn = fmaxf(sqrtf(m2a), MINN);
  float s = tanh_(mxn/xnh*rr)/(mxn*SQC);
  float nr = s*mxn;
  if(nr > MAXN){ s *= MAXN/nr; nr = MAXN; }
  float xy = s*meba, x2 = nr*nr;
  float den = fmaxf(1.f + 2.f*CC*xy + CC*CC*x2*y2, MINN);
  float A = (1.f + 2.f*CC*xy + CC*y2)/den;
  float Bc = (1.f - CC*x2)/den;
  float n3 = sqrtf(fmaxf(A*A*x2 + 2.f*A*Bc*xy + Bc*Bc*y2, 0.f));
  float rho = (n3 > MAXN) ? MAXN/n3 : 1.f;
  float nv = fminf(n3, MAXN);
  float lr = lamv(nv)*rho;
  THW r; r.te = lr*(A*s*mw1 + Bc*ebw1); r.th2 = lr*(A*s*mw2 + Bc*ebw2);
  return r;
}
struct AG { float wge, g2; };
__device__ __forceinline__ AG attn(float d1, float d2, float thte, float thth,
                                   float rr, float xnh, float b_e, float b_h){
  float a_e = 0.5f*(d1 - thte) + b_e;
  float a_h = 0.5f*(thth - d2) + b_h;
  float mx = fmaxf(a_e, a_h);
  float ee = __expf(a_e - mx), eh = __expf(a_h - mx);
  float inv = 1.f/(ee + eh);
  AG r; r.wge = ee*inv;
  float wgh = eh*inv;
  float inner = wgh*rr;
  float scl2 = tanh_(inner)/(xnh*SQC);
  float nn = scl2*xnh;
  if(nn > MAXN){ scl2 *= MAXN/nn; nn = MAXN; }
  r.g2 = lamv(nn)*scl2;
  return r;
}

// ---------------- fused setup: transpose-pad weights + folded constants ------
__global__ void k_setup(const float* __restrict__ Wh1, const float* __restrict__ Wh2,
                        const float* __restrict__ Wh3, const float* __restrict__ Wah,
                        const float* __restrict__ We1, const float* __restrict__ We2,
                        const float* __restrict__ We3,
                        const float* __restrict__ Wae, const float* __restrict__ bae,
                        const float* __restrict__ bh1, const float* __restrict__ bh2,
                        const float* __restrict__ bh3, const float* __restrict__ bah,
                        const float* __restrict__ Wte, const float* __restrict__ Wth,
                        const float* __restrict__ be1, const float* __restrict__ be2,
                        const float* __restrict__ be3, float* __restrict__ ws){
  const int blk = blockIdx.x, tid = threadIdx.x;
  if(blk < 280){
    const int row = blk*2 + (tid >> 7);   // 0..559
    const int j   = tid & 127;
    const float* W; int OUT, K, kk, dst;
    if(row < 32)       { W=Wh1; OUT=80;  K=32;  kk=row;      dst=WTH1; }
    else if(row < 112) { W=Wh2; OUT=104; K=80;  kk=row-32;   dst=WTH2; }
    else if(row < 216) { W=Wh3; OUT=128; K=104; kk=row-112;  dst=WTH3; }
    else if(row < 344) { W=Wah; OUT=128; K=128; kk=row-216;  dst=WTAH; }
    else if(row < 376) { W=We1; OUT=80;  K=32;  kk=row-344;  dst=WTE1; }
    else if(row < 456) { W=We2; OUT=104; K=80;  kk=row-376;  dst=WTE2; }
    else               { W=We3; OUT=128; K=104; kk=row-456;  dst=WTE3; }
    ws[dst + kk*128 + j] = (j < OUT) ? W[j*K + kk] : 0.f;
    return;
  }
  // -------- constants block --------
  {
    const int which = tid >> 7, k = tid & 127;
    const float* wv = which ? Wth : Wte;
    float s = 0.f;
#pragma unroll 4
    for(int j=0;j<128;++j) s += Wae[j*128+k] * wv[j];
    ws[(which ? U2o : U1o) + k] = s;
  }
  if(tid < 128){
    ws[BE1+tid] = (tid < 80)  ? be1[tid] : 0.f;
    ws[BE2+tid] = (tid < 104) ? be2[tid] : 0.f;
    ws[BE3+tid] = be3[tid];
  }
  if(tid < 64){
    const int l = tid;
    float p1=0.f, p2=0.f;
    for(int j=l;j<128;j+=64){ p1 += bae[j]*Wte[j]; p2 += bae[j]*Wth[j]; }
    p1 = wsum64(p1); p2 = wsum64(p2);
    if(l==0){ ws[SCo+0]=p1; ws[SCo+1]=p2; }
    const float* bs[4] = {bh1,bh2,bh3,bah};
    const int dims[4]  = {80,104,128,128};
    const int offs[4]  = {EB1,EB2,EB3,EBA};
    for(int v=0;v<4;++v){
      const float* bp = bs[v]; const int D = dims[v];
      float q = 0.f;
      for(int j=l;j<D;j+=64) q += bp[j]*bp[j];
      q = wsum64(q);
      float nb = fmaxf(sqrtf(q), MINN);
      float th = tanhf(fminf(fmaxf(SQC*nb,-15.f),15.f));
      float coef = th/(SQC*nb);
      float ne = th/SQC;
      if(ne > MAXN){ coef *= MAXN/ne; ne = MAXN; }
      for(int j=l;j<D;j+=64) ws[offs[v]+j] = coef*bp[j];
      for(int j=D+l;j<128;j+=64) ws[offs[v]+j] = 0.f;   // pad
      if(l==0) ws[SCo+2+v] = ne*ne;
      if(v==3){
        float e1=0.f, e2=0.f;
        for(int j=l;j<D;j+=64){ e1 += bp[j]*Wte[j]; e2 += bp[j]*Wth[j]; }
        e1 = wsum64(e1)*coef; e2 = wsum64(e2)*coef;
        if(l==0){ ws[SCo+6]=e1; ws[SCo+7]=e2; }
      }
    }
  }
}

// ---------------- finishing kernel: combine 8 sixteenths + classifier --------
__global__ void k_fin(const float* __restrict__ ws, const float* __restrict__ bf1,
                      const float* __restrict__ Wf2, const float* __restrict__ bf2,
                      float* __restrict__ out){
  const int r = blockIdx.x*64 + threadIdx.x;   // grid 16 x 64 = 1024 rows
  const float* p = ws + PART + (size_t)r*80;   // 8 blocks x 10
  float f1[10];
#pragma unroll
  for(int i=0;i<10;++i){
    float s = 0.f;
#pragma unroll
    for(int g=0;g<8;++g) s += p[g*10+i];
    // each token was counted 4x by the owner-lane redundancy -> /(128*4)
    f1[i] = fmaxf(s*(1.f/512.f) + bf1[i], 0.f);
  }
#pragma unroll
  for(int o=0;o<10;++o){
    float a = bf2[o];
#pragma unroll
    for(int k=0;k<10;++k) a = fmaf(Wf2[o*10+k], f1[k], a);
    out[r*10 + o] = a;
  }
}

// ---------------- GEMM inner: 8 feat x 4 tok register tile per lane ----------
__device__ __forceinline__ void ld8(const float* __restrict__ p, float (&v)[8]){
  float4 a = *(const float4*)p, b = *(const float4*)(p+4);
  v[0]=a.x; v[1]=a.y; v[2]=a.z; v[3]=a.w; v[4]=b.x; v[5]=b.y; v[6]=b.z; v[7]=b.w;
}

// unroll 2: bounded in-flight load pipeline (fits the 64-VGPR class, no spills)
template<int K, bool XG, bool XSQ>
__device__ __forceinline__ void gemmw(const float* __restrict__ wt,
                                      const float* __restrict__ xg,
                                      const float* __restrict__ ACT,
                                      int fj, int tt, float (&acc)[4][8], float (&xsq)[4]){
#pragma unroll
  for(int i=0;i<4;++i)
#pragma unroll
    for(int j=0;j<8;++j) acc[i][j] = 0.f;
  const int wo = fj*8, xo = tt*4;
#pragma unroll 2
  for(int k=0;k<K;++k){
    float4 w0 = *(const float4*)(wt + k*128 + wo);
    float4 w1 = *(const float4*)(wt + k*128 + wo + 4);
    float4 xa;
    if(XG) xa = *(const float4*)(xg + k*128 + xo);
    else   xa = *(const float4*)(ACT + k*ASTR + xo);
    float xv[4] = {xa.x,xa.y,xa.z,xa.w};
    float wv[8] = {w0.x,w0.y,w0.z,w0.w,w1.x,w1.y,w1.z,w1.w};
#pragma unroll
    for(int i=0;i<4;++i){
      if(XSQ) xsq[i] = fmaf(xv[i], xv[i], xsq[i]);
#pragma unroll
      for(int j=0;j<8;++j) acc[i][j] = fmaf(xv[i], wv[j], acc[i][j]);
    }
  }
}

__device__ __forceinline__ void wACT(float* __restrict__ ACT, const float (&acc)[4][8],
                                     int fj, int tt){
#pragma unroll
  for(int j=0;j<8;++j){
    float4 a = {acc[0][j],acc[1][j],acc[2][j],acc[3][j]};
    *(float4*)(ACT + (fj*8+j)*ASTR + tt*4) = a;
  }
}

// compile-time scheduling fence (live-range segmentation for the allocator)
__device__ __forceinline__ void sfence(){ __builtin_amdgcn_sched_barrier(0); }

// ---------------- main kernel: 1 block = 1 WAVE (64 thr) per 16 tokens -------
// R9 structure (barrier-free, spill-free) + DPP cross-lane: rtj/broadcasts
// moved from the per-CU-shared DS pipe (ds_swizzle, ~30cy/step) to VALU DPP
// (~4cy/step). Removes ~600 DS wave-ops and ~3.5K cycles of serial chain
// latency per wave -> attacks the occupancy-insensitive stall component.
__global__ __launch_bounds__(64) void k_main(
    const float* __restrict__ x,
    const float* __restrict__ Wf1, const float* __restrict__ Wte,
    const float* __restrict__ bte, const float* __restrict__ Wth,
    const float* __restrict__ bth, float* __restrict__ ws){
  __shared__ float ACT[128*ASTR];       // 8704 B
  __shared__ float ZH[160];             // 10 classes x 16 tokens
  const int tid = threadIdx.x, fj = tid & 15, tt = tid >> 4;
  const int b = blockIdx.x, row = b >> 3, q = b & 7;
  const int own = fj & 3;               // token (within my tt group) I own
  const float* xg = x + (size_t)row*4096 + q*16;

  // wave-uniform constants (scalar loads)
  const float c1  = ws[SCo+0], c2  = ws[SCo+1];
  const float y21 = ws[SCo+2], y22 = ws[SCo+3], y23 = ws[SCo+4], y2a = ws[SCo+5];
  const float ew1 = ws[SCo+6], ew2 = ws[SCo+7];
  const float btev = bte[0], bthv = bth[0];

  float acc[4][8];
  float xsq[4];
#pragma unroll
  for(int i=0;i<4;++i) xsq[i] = 0.f;

  // owner-lane per-token state
  float nfO = 0.f, xnhO = 1.f, rrO = 0.f, tteO = 0.f, tthO = 0.f;

  // ================= H1: 32 -> 128(pad80), mob_relu =================
  {
    gemmw<32,true,true>(ws+WTH1, xg, ACT, fj, tt, acc, xsq);
    float ebv[8]; ld8(ws+EB1+fj*8, ebv);
    float sO = 0.f, eO = 0.f;
#pragma unroll
    for(int i=0;i<4;++i){
      float s=0.f, e=0.f;
#pragma unroll
      for(int j=0;j<8;++j){ s = fmaf(acc[i][j],acc[i][j],s); e = fmaf(acc[i][j],ebv[j],e); }
      s = rtj(s); e = rtj(e);                   // row16 sums in ALL lanes (DPP)
      if(own==i){ sO = s; eO = e; }             // running owner-select
    }
    EX e0 = exp0(sel4(xsq, own));
    HS h  = hyper_chain(sO*e0.scl*e0.scl, eO*e0.scl, e0.nh, y21);
    float lam = lamv(h.nv);
    float Aw = lam*h.ca*e0.scl, Bw = lam*h.cb;
    float Ab4[4] = {qbc<0>(Aw), qbc<1>(Aw), qbc<2>(Aw), qbc<3>(Aw)};
    float Bb4[4] = {qbc<0>(Bw), qbc<1>(Bw), qbc<2>(Bw), qbc<3>(Bw)};
    float s2O = 0.f;
#pragma unroll
    for(int i=0;i<4;++i){
      float s2 = 0.f;
#pragma unroll
      for(int j=0;j<8;++j){
        float v = fmaxf(fmaf(Ab4[i], acc[i][j], Bb4[i]*ebv[j]), 0.f);
        acc[i][j] = v; s2 = fmaf(v,v,s2);
      }
      s2 = rtj(s2);
      if(own==i) s2O = s2;
    }
    TT tr = tail_relu(s2O);
    nfO = tr.nf;
    float tb4[4] = {qbc<0>(tr.tau), qbc<1>(tr.tau), qbc<2>(tr.tau), qbc<3>(tr.tau)};
#pragma unroll
    for(int i=0;i<4;++i)
#pragma unroll
      for(int j=0;j<8;++j) acc[i][j] *= tb4[i];
    wACT(ACT, acc, fj, tt);
  }
  sfence();

  // ================= H2: 80 -> 128(pad104), mob_relu =================
  {
    gemmw<80,false,false>(ws+WTH2, nullptr, ACT, fj, tt, acc, xsq);
    float ebv[8]; ld8(ws+EB2+fj*8, ebv);
    float sO = 0.f, eO = 0.f;
#pragma unroll
    for(int i=0;i<4;++i){
      float s=0.f, e=0.f;
#pragma unroll
      for(int j=0;j<8;++j){ s = fmaf(acc[i][j],acc[i][j],s); e = fmaf(acc[i][j],ebv[j],e); }
      s = rtj(s); e = rtj(e);
      if(own==i){ sO = s; eO = e; }
    }
    HS h = hyper_chain(sO, eO, nfO, y22);
    float lam = lamv(h.nv);
    float Aw = lam*h.ca, Bw = lam*h.cb;
    float Ab4[4] = {qbc<0>(Aw), qbc<1>(Aw), qbc<2>(Aw), qbc<3>(Aw)};
    float Bb4[4] = {qbc<0>(Bw), qbc<1>(Bw), qbc<2>(Bw), qbc<3>(Bw)};
    float s2O = 0.f;
#pragma unroll
    for(int i=0;i<4;++i){
      float s2 = 0.f;
#pragma unroll
      for(int j=0;j<8;++j){
        float v = fmaxf(fmaf(Ab4[i], acc[i][j], Bb4[i]*ebv[j]), 0.f);
        acc[i][j] = v; s2 = fmaf(v,v,s2);
      }
      s2 = rtj(s2);
      if(own==i) s2O = s2;
    }
    TT tr = tail_relu(s2O);
    nfO = tr.nf;
    float tb4[4] = {qbc<0>(tr.tau), qbc<1>(tr.tau), qbc<2>(tr.tau), qbc<3>(tr.tau)};
#pragma unroll
    for(int i=0;i<4;++i)
#pragma unroll
      for(int j=0;j<8;++j) acc[i][j] *= tb4[i];
    wACT(ACT, acc, fj, tt);
  }
  sfence();

  // ================= H3: 104 -> 128, p_linear only (out_h) =================
  {
    gemmw<104,false,false>(ws+WTH3, nullptr, ACT, fj, tt, acc, xsq);
    float ebv[8]; ld8(ws+EB3+fj*8, ebv);
    float sO = 0.f, eO = 0.f;
#pragma unroll
    for(int i=0;i<4;++i){
      float s=0.f, e=0.f;
#pragma unroll
      for(int j=0;j<8;++j){ s = fmaf(acc[i][j],acc[i][j],s); e = fmaf(acc[i][j],ebv[j],e); }
      s = rtj(s); e = rtj(e);
      if(own==i){ sO = s; eO = e; }
    }
    HS h = hyper_chain(sO, eO, nfO, y23);
    xnhO = fmaxf(h.nv, MINN);
    rrO  = art_(SQC*xnhO);
    float ca4[4] = {qbc<0>(h.ca), qbc<1>(h.ca), qbc<2>(h.ca), qbc<3>(h.ca)};
    float cb4[4] = {qbc<0>(h.cb), qbc<1>(h.cb), qbc<2>(h.cb), qbc<3>(h.cb)};
#pragma unroll
    for(int i=0;i<4;++i)
#pragma unroll
      for(int j=0;j<8;++j) acc[i][j] = fmaf(ca4[i], acc[i][j], cb4[i]*ebv[j]);
    wACT(ACT, acc, fj, tt);
    // zh[ic][token] = Wf1[ic,128+.] . out_h  -> LDS (not registers)
#pragma unroll
    for(int ic=0;ic<10;++ic){
      float wf[8]; ld8(Wf1 + ic*256 + 128 + fj*8, wf);
#pragma unroll
      for(int i=0;i<4;++i){
        float s=0.f;
#pragma unroll
        for(int j=0;j<8;++j) s = fmaf(acc[i][j], wf[j], s);
        s = rtj(s);
        if(fj==0) ZH[ic*16 + tt*4 + i] = s;
      }
    }
  }
  sfence();

  // ================= Wah pass: 4 reductions of mx = Wah . out_h =============
  {
    gemmw<128,false,false>(ws+WTAH, nullptr, ACT, fj, tt, acc, xsq);
    float w1v[8], w2v[8], eav[8];
    ld8(Wte + fj*8, w1v); ld8(Wth + fj*8, w2v); ld8(ws+EBA+fj*8, eav);
    float aO=0.f, bO=0.f, cO=0.f, dO=0.f;
#pragma unroll
    for(int i=0;i<4;++i){
      float s0=0.f,s1=0.f,s2=0.f,s3=0.f;
#pragma unroll
      for(int j=0;j<8;++j){
        float m = acc[i][j];
        s0 = fmaf(m,m,s0); s1 = fmaf(m,w1v[j],s1);
        s2 = fmaf(m,w2v[j],s2); s3 = fmaf(m,eav[j],s3);
      }
      s0=rtj(s0); s1=rtj(s1); s2=rtj(s2); s3=rtj(s3);
      if(own==i){ aO=s0; bO=s1; cO=s2; dO=s3; }
    }
    THW a = ahchain(aO, bO, cO, dO, xnhO, rrO, y2a, ew1, ew2);
    tteO = a.te; tthO = a.th2;
  }
  sfence();

  // ================= E1: relu(We1 x + be1) =================
  {
    gemmw<32,true,false>(ws+WTE1, xg, ACT, fj, tt, acc, xsq);
    float bev[8]; ld8(ws+BE1+fj*8, bev);
#pragma unroll
    for(int i=0;i<4;++i)
#pragma unroll
      for(int j=0;j<8;++j) acc[i][j] = fmaxf(acc[i][j]+bev[j], 0.f);
    wACT(ACT, acc, fj, tt);
  }
  sfence();
  // ================= E2 =================
  {
    gemmw<80,false,false>(ws+WTE2, nullptr, ACT, fj, tt, acc, xsq);
    float bev[8]; ld8(ws+BE2+fj*8, bev);
#pragma unroll
    for(int i=0;i<4;++i)
#pragma unroll
      for(int j=0;j<8;++j) acc[i][j] = fmaxf(acc[i][j]+bev[j], 0.f);
    wACT(ACT, acc, fj, tt);
  }
  sfence();
  // ======== E3: out_e (in regs) -> d1,d2, ze; attention; partials ========
  {
    gemmw<104,false,false>(ws+WTE3, nullptr, ACT, fj, tt, acc, xsq);
    float bev[8], u1v[8], u2v[8];
    ld8(ws+BE3+fj*8, bev); ld8(ws+U1o+fj*8, u1v); ld8(ws+U2o+fj*8, u2v);
    float s1O = 0.f, s2O = 0.f;
#pragma unroll
    for(int i=0;i<4;++i){
      float s1=0.f, s2=0.f;
#pragma unroll
      for(int j=0;j<8;++j){
        float v = fmaxf(acc[i][j]+bev[j], 0.f);
        acc[i][j] = v;
        s1 = fmaf(v,u1v[j],s1); s2 = fmaf(v,u2v[j],s2);
      }
      s1 = rtj(s1); s2 = rtj(s2);
      if(own==i){ s1O = s1; s2O = s2; }
    }
    AG g = attn(s1O + c1, s2O + c2, tteO, tthO, rrO, xnhO, btev, bthv);
    // classifier partials (each token counted 4x by owner redundancy; k_fin /512)
#pragma unroll
    for(int ic=0;ic<10;++ic){
      float wf[8]; ld8(Wf1 + ic*256 + fj*8, wf);
      float zO = 0.f;
#pragma unroll
      for(int i=0;i<4;++i){
        float s=0.f;
#pragma unroll
        for(int j=0;j<8;++j) s = fmaf(acc[i][j], wf[j], s);
        s = rtj(s);
        if(own==i) zO = s;
      }
      float p = g.wge*zO + g.g2*ZH[ic*16 + tt*4 + own];
      p = wsum(p);
      if(tid == 0) ws[PART + (size_t)b*10 + ic] = p;
    }
  }
}

extern "C" void kernel_launch(void* const* d_in, const int* in_sizes, int n_in,
                              void* d_out, int out_size, void* d_ws, size_t ws_size,
                              hipStream_t stream){
  (void)in_sizes; (void)n_in; (void)out_size; (void)ws_size;
  const float* x   = (const float*)d_in[0];
  const float* We1 = (const float*)d_in[1];
  const float* be1 = (const float*)d_in[2];
  const float* We2 = (const float*)d_in[3];
  const float* be2 = (const float*)d_in[4];
  const float* We3 = (const float*)d_in[5];
  const float* be3 = (const float*)d_in[6];
  const float* Wh1 = (const float*)d_in[7];
  const float* bh1 = (const float*)d_in[8];
  const float* Wh2 = (const float*)d_in[9];
  const float* bh2 = (const float*)d_in[10];
  const float* Wh3 = (const float*)d_in[11];
  const float* bh3 = (const float*)d_in[12];
  const float* Wae = (const float*)d_in[13];
  const float* bae = (const float*)d_in[14];
  const float* Wah = (const float*)d_in[15];
  const float* bah = (const float*)d_in[16];
  const float* Wte = (const float*)d_in[17];
  const float* bte = (const float*)d_in[18];
  const float* Wth = (const float*)d_in[19];
  const float* bth = (const float*)d_in[20];
  const float* Wf1 = (const float*)d_in[21];
  const float* bf1 = (const float*)d_in[22];
  const float* Wf2 = (const float*)d_in[23];
  const float* bf2 = (const float*)d_in[24];
  float* ws  = (float*)d_ws;
  float* out = (float*)d_out;

  hipLaunchKernelGGL(k_setup, dim3(281), dim3(256), 0, stream,
                     Wh1, Wh2, Wh3, Wah, We1, We2, We3,
                     Wae, bae, bh1, bh2, bh3, bah, Wte, Wth, be1, be2, be3, ws);

  hipLaunchKernelGGL(k_main, dim3(8192), dim3(64), 0, stream,
                     x, Wf1, Wte, bte, Wth, bth, ws);

  hipLaunchKernelGGL(k_fin, dim3(16), dim3(64), 0, stream,
                     ws, bf1, Wf2, bf2, out);
}